// Round 1
// baseline (502.487 us; speedup 1.0000x reference)
//
#include <hip/hip_runtime.h>

typedef unsigned short u16;
typedef __bf16 bf16x8 __attribute__((ext_vector_type(8)));
typedef float f32x4 __attribute__((ext_vector_type(4)));

#define B_ 4
#define S_ 2048
#define D_ 1024
#define H_ 16

__device__ inline u16 f2bf(float f) {
  unsigned u = __float_as_uint(f);
  u = u + 0x7fffu + ((u >> 16) & 1u);
  return (u16)(u >> 16);
}
__device__ inline float bf2f(u16 h) {
  return __uint_as_float(((unsigned)h) << 16);
}
__device__ inline void gload_lds16(const u16* g, u16* l) {
  __builtin_amdgcn_global_load_lds((const __attribute__((address_space(1))) void*)g,
                                   (__attribute__((address_space(3))) void*)l, 16, 0, 0);
}

// ---------------- f32 -> bf16 convert (vectorized) ----------------
__global__ __launch_bounds__(256) void k_f32_to_bf16(const float* __restrict__ src,
                                                     u16* __restrict__ dst, int n4) {
  int i = blockIdx.x * 256 + threadIdx.x;
  if (i >= n4) return;
  float4 v = reinterpret_cast<const float4*>(src)[i];
  ushort4 o;
  o.x = f2bf(v.x); o.y = f2bf(v.y); o.z = f2bf(v.z); o.w = f2bf(v.w);
  reinterpret_cast<ushort4*>(dst)[i] = o;
}

// ---------------- RoPE cos/sin table: [S][32] float2 ----------------
__global__ __launch_bounds__(256) void k_rope_table(const int* __restrict__ pos,
                                                    float2* __restrict__ tab) {
  int idx = blockIdx.x * 256 + threadIdx.x;
  if (idx >= S_ * 32) return;
  int s = idx >> 5, i = idx & 31;
  float freq = powf(10000.0f, -(float)i * (1.0f / 32.0f));  // precise powf (error budget!)
  float ang = (float)pos[s] * freq;
  float sn, c;
  sincosf(ang, &sn, &c);
  tab[idx] = make_float2(c, sn);
}

// ---------------- RoPE apply in-place on bf16 [B*S][D], pairs within heads ----
__global__ __launch_bounds__(256) void k_rope_apply(u16* __restrict__ qk,
                                                    const float2* __restrict__ tab,
                                                    float scale) {
  int idx = blockIdx.x * 256 + threadIdx.x;     // B*S*H*32 = 4194304
  if (idx >= B_ * S_ * H_ * 32) return;
  int i = idx & 31;
  int h = (idx >> 5) & 15;
  int s = (idx >> 9) & 2047;
  int b = idx >> 20;
  float2 cs = tab[(s << 5) | i];
  size_t base = ((size_t)(b * S_ + s) << 10) + h * 64 + 2 * i;
  ushort2 xv = *reinterpret_cast<ushort2*>(qk + base);
  float x1 = bf2f(xv.x), x2 = bf2f(xv.y);
  ushort2 o;
  o.x = f2bf((x1 * cs.x - x2 * cs.y) * scale);
  o.y = f2bf((x1 * cs.y + x2 * cs.x) * scale);
  *reinterpret_cast<ushort2*>(qk + base) = o;
}

// ---------------- GEMM: C[M][N] = A[M][K] * Bw[N][K]^T  (both K-major bf16) ----
// m97 structure: 128x128 tile, BK=32, 4 waves (2x2 of 64x64), global_load_lds w=16.
template <int OUT_BF16>
__global__ __launch_bounds__(256) void k_gemm_bt(const u16* __restrict__ A,
                                                 const u16* __restrict__ Bw,
                                                 void* __restrict__ C,
                                                 int M, int N, int K) {
  __shared__ u16 As[128 * 32];
  __shared__ u16 Bs[128 * 32];
  const int nbx = N >> 7;
  const int bx = blockIdx.x % nbx;
  const int by = blockIdx.x / nbx;
  const int m0 = by << 7, n0 = bx << 7;
  const int tid = threadIdx.x;
  const int lane = tid & 63;
  const int wv = tid >> 6;
  const int wm = (wv >> 1) << 6;
  const int wn = (wv & 1) << 6;
  const int r = lane & 15, g = lane >> 4;

  f32x4 acc[4][4] = {};

  const int o0 = tid << 4;       // byte offset in 8KB tile, issue 0
  const int o1 = o0 + 4096;      // issue 1
  const int am0 = o0 >> 6, ak0 = (o0 & 63) >> 1;
  const int am1 = o1 >> 6, ak1 = (o1 & 63) >> 1;

  for (int k0 = 0; k0 < K; k0 += 32) {
    gload_lds16(A + (size_t)(m0 + am0) * K + k0 + ak0, As + (o0 >> 1));
    gload_lds16(A + (size_t)(m0 + am1) * K + k0 + ak1, As + (o1 >> 1));
    gload_lds16(Bw + (size_t)(n0 + am0) * K + k0 + ak0, Bs + (o0 >> 1));
    gload_lds16(Bw + (size_t)(n0 + am1) * K + k0 + ak1, Bs + (o1 >> 1));
    __syncthreads();
    bf16x8 af[4], bfr[4];
#pragma unroll
    for (int i = 0; i < 4; i++)
      af[i] = *reinterpret_cast<const bf16x8*>(&As[(wm + i * 16 + r) * 32 + g * 8]);
#pragma unroll
    for (int t = 0; t < 4; t++)
      bfr[t] = *reinterpret_cast<const bf16x8*>(&Bs[(wn + t * 16 + r) * 32 + g * 8]);
#pragma unroll
    for (int i = 0; i < 4; i++)
#pragma unroll
      for (int t = 0; t < 4; t++)
        acc[i][t] = __builtin_amdgcn_mfma_f32_16x16x32_bf16(af[i], bfr[t], acc[i][t], 0, 0, 0);
    __syncthreads();
  }

#pragma unroll
  for (int i = 0; i < 4; i++) {
#pragma unroll
    for (int t = 0; t < 4; t++) {
      const int row = m0 + wm + i * 16 + g * 4;
      const int col = n0 + wn + t * 16 + r;
#pragma unroll
      for (int j = 0; j < 4; j++) {
        float v = acc[i][t][j];
        if (OUT_BF16)
          ((u16*)C)[(size_t)(row + j) * N + col] = f2bf(v);
        else
          ((float*)C)[(size_t)(row + j) * N + col] = v;
      }
    }
  }
}

// ---------------- V transpose: Vb[B*S][D] -> Vt[bh][d(64)][s(2048)] ----------
__global__ __launch_bounds__(256) void k_transpose_v(const u16* __restrict__ Vb,
                                                     u16* __restrict__ Vt) {
  __shared__ u16 tile[64][65];
  int bh = blockIdx.x >> 5;
  int st = blockIdx.x & 31;
  int b = bh >> 4, h = bh & 15;
  int s0 = st << 6;
  int tid = threadIdx.x;
#pragma unroll
  for (int rr = 0; rr < 16; rr++) {
    int idx = rr * 256 + tid;
    int sl = idx >> 6, d = idx & 63;
    tile[d][sl] = Vb[(size_t)(b * S_ + s0 + sl) * 1024 + h * 64 + d];
  }
  __syncthreads();
#pragma unroll
  for (int rr = 0; rr < 16; rr++) {
    int idx = rr * 256 + tid;
    int d = idx >> 6, sl = idx & 63;
    Vt[(size_t)(bh * 64 + d) * 2048 + s0 + sl] = tile[d][sl];
  }
}

// ---------------- Flash attention: 1 wave per 16 q-rows, KBLK=32 -------------
// Q pre-scaled by 1/8. Layouts: Q,K [B*S][D] bf16 ; Vt [bh][64][2048] bf16.
__global__ __launch_bounds__(64) void k_attn(const u16* __restrict__ Q,
                                             const u16* __restrict__ Kb,
                                             const u16* __restrict__ Vt,
                                             u16* __restrict__ O) {
  __shared__ u16 P_lds[16 * 32];
  int bid = blockIdx.x;
  int qt = bid & 127;
  int bh = bid >> 7;
  int b = bh >> 4, h = bh & 15;
  int lane = threadIdx.x;
  int g = lane >> 4, r = lane & 15;
  int q0 = qt << 4;

  const u16* qrow = Q + (size_t)(b * S_ + q0 + r) * 1024 + h * 64;
  bf16x8 qf0 = *reinterpret_cast<const bf16x8*>(qrow + g * 8);
  bf16x8 qf1 = *reinterpret_cast<const bf16x8*>(qrow + 32 + g * 8);

  f32x4 o_acc[4] = {};
  float m_run[4], l_run[4];
#pragma unroll
  for (int j = 0; j < 4; j++) { m_run[j] = -1e30f; l_run[j] = 0.f; }

  const u16* Kbase = Kb + (size_t)(b * S_) * 1024 + h * 64;
  const u16* Vbase = Vt + (size_t)bh * 64 * 2048;

  const int kend = q0 + 16;
  for (int k0 = 0; k0 < kend; k0 += 32) {
    f32x4 sacc[2] = {};
#pragma unroll
    for (int st = 0; st < 2; st++) {
      const u16* krow = Kbase + (size_t)(k0 + st * 16 + r) * 1024;
      bf16x8 kf0 = *reinterpret_cast<const bf16x8*>(krow + g * 8);
      bf16x8 kf1 = *reinterpret_cast<const bf16x8*>(krow + 32 + g * 8);
      sacc[st] = __builtin_amdgcn_mfma_f32_16x16x32_bf16(qf0, kf0, sacc[st], 0, 0, 0);
      sacc[st] = __builtin_amdgcn_mfma_f32_16x16x32_bf16(qf1, kf1, sacc[st], 0, 0, 0);
    }
    float sv[2][4];
#pragma unroll
    for (int st = 0; st < 2; st++)
#pragma unroll
      for (int j = 0; j < 4; j++) sv[st][j] = sacc[st][j];
    if (k0 + 31 > q0) {
#pragma unroll
      for (int st = 0; st < 2; st++) {
        int col = k0 + st * 16 + r;
#pragma unroll
        for (int j = 0; j < 4; j++) {
          int row = q0 + g * 4 + j;
          if (col > row) sv[st][j] = -1e30f;
        }
      }
    }
    float pp[2][4];
#pragma unroll
    for (int j = 0; j < 4; j++) {
      float t = fmaxf(sv[0][j], sv[1][j]);
#pragma unroll
      for (int off = 1; off < 16; off <<= 1) t = fmaxf(t, __shfl_xor(t, off));
      float mnew = fmaxf(m_run[j], t);
      float sc = __expf(m_run[j] - mnew);
      pp[0][j] = __expf(sv[0][j] - mnew);
      pp[1][j] = __expf(sv[1][j] - mnew);
      float s = pp[0][j] + pp[1][j];
#pragma unroll
      for (int off = 1; off < 16; off <<= 1) s += __shfl_xor(s, off);
      l_run[j] = l_run[j] * sc + s;
      m_run[j] = mnew;
#pragma unroll
      for (int t2 = 0; t2 < 4; t2++) o_acc[t2][j] *= sc;
    }
    // P (f32, D-layout) -> bf16 -> LDS -> A-frag layout
#pragma unroll
    for (int st = 0; st < 2; st++)
#pragma unroll
      for (int j = 0; j < 4; j++)
        P_lds[(g * 4 + j) * 32 + st * 16 + r] = f2bf(pp[st][j]);
    __syncthreads();
    bf16x8 pf = *reinterpret_cast<const bf16x8*>(&P_lds[r * 32 + g * 8]);
#pragma unroll
    for (int t = 0; t < 4; t++) {
      bf16x8 vf = *reinterpret_cast<const bf16x8*>(Vbase + (size_t)(t * 16 + r) * 2048 + k0 + g * 8);
      o_acc[t] = __builtin_amdgcn_mfma_f32_16x16x32_bf16(pf, vf, o_acc[t], 0, 0, 0);
    }
    __syncthreads();
  }

  u16* orow = O + (size_t)(b * S_ + q0) * 1024 + h * 64;
#pragma unroll
  for (int t = 0; t < 4; t++)
#pragma unroll
    for (int j = 0; j < 4; j++) {
      float v = o_acc[t][j] / l_run[j];
      orow[(size_t)(g * 4 + j) * 1024 + t * 16 + r] = f2bf(v);
    }
}

// ---------------- host side ----------------
extern "C" void kernel_launch(void* const* d_in, const int* in_sizes, int n_in,
                              void* d_out, int out_size, void* d_ws, size_t ws_size,
                              hipStream_t stream) {
  const float* x  = (const float*)d_in[0];
  const int*   pos = (const int*)d_in[1];
  const float* Wq = (const float*)d_in[2];
  const float* Wk = (const float*)d_in[3];
  const float* Wv = (const float*)d_in[4];
  const float* Wo = (const float*)d_in[5];
  float* out = (float*)d_out;

  char* ws = (char*)d_ws;
  size_t off = 0;
  auto alloc = [&](size_t bytes) {
    void* p = ws + off;
    off += (bytes + 255) & ~(size_t)255;
    return p;
  };
  const size_t XB = (size_t)8192 * 1024 * 2;  // bf16 [B*S][D]
  u16* xb  = (u16*)alloc(XB);
  u16* wqb = (u16*)alloc((size_t)1024 * 1024 * 2);
  u16* wkb = (u16*)alloc((size_t)1024 * 1024 * 2);
  u16* wvb = (u16*)alloc((size_t)1024 * 1024 * 2);
  u16* wob = (u16*)alloc((size_t)1024 * 1024 * 2);
  u16* qb  = (u16*)alloc(XB);
  u16* kb  = (u16*)alloc(XB);
  u16* vb  = (u16*)alloc(XB);
  u16* vt  = (u16*)alloc(XB);
  float2* tab = (float2*)alloc((size_t)2048 * 32 * sizeof(float2));
  u16* ob = vb;  // alias: vb dead after transpose

  // converts
  k_f32_to_bf16<<<8192, 256, 0, stream>>>(x, xb, 2097152);
  k_f32_to_bf16<<<1024, 256, 0, stream>>>(Wq, wqb, 262144);
  k_f32_to_bf16<<<1024, 256, 0, stream>>>(Wk, wkb, 262144);
  k_f32_to_bf16<<<1024, 256, 0, stream>>>(Wv, wvb, 262144);
  k_f32_to_bf16<<<1024, 256, 0, stream>>>(Wo, wob, 262144);
  k_rope_table<<<256, 256, 0, stream>>>(pos, tab);

  // QKV projections (M=8192, N=1024, K=1024) -> 512 blocks each
  k_gemm_bt<1><<<512, 256, 0, stream>>>(xb, wqb, qb, 8192, 1024, 1024);
  k_gemm_bt<1><<<512, 256, 0, stream>>>(xb, wkb, kb, 8192, 1024, 1024);
  k_gemm_bt<1><<<512, 256, 0, stream>>>(xb, wvb, vb, 8192, 1024, 1024);

  // RoPE (Q also gets the 1/sqrt(dk)=0.125 scale folded in)
  k_rope_apply<<<16384, 256, 0, stream>>>(qb, tab, 0.125f);
  k_rope_apply<<<16384, 256, 0, stream>>>(kb, tab, 1.0f);

  // V transpose for PV fragment loads
  k_transpose_v<<<2048, 256, 0, stream>>>(vb, vt);

  // flash attention: 64 (b,h) * 128 q-tiles
  k_attn<<<8192, 64, 0, stream>>>(qb, kb, vt, ob);

  // output projection -> f32 out
  k_gemm_bt<0><<<512, 256, 0, stream>>>(ob, wob, out, 8192, 1024, 1024);
}

// Round 3
// 350.848 us; speedup vs baseline: 1.4322x; 1.4322x over previous
//
#include <hip/hip_runtime.h>

typedef unsigned short u16;
typedef __bf16 bf16x8 __attribute__((ext_vector_type(8)));
typedef float f32x4 __attribute__((ext_vector_type(4)));

#define B_ 4
#define S_ 2048
#define D_ 1024
#define H_ 16

__device__ inline u16 f2bf(float f) {
  unsigned u = __float_as_uint(f);
  u = u + 0x7fffu + ((u >> 16) & 1u);
  return (u16)(u >> 16);
}
__device__ inline float bf2f(u16 h) {
  return __uint_as_float(((unsigned)h) << 16);
}
__device__ inline void gload_lds16(const u16* g, u16* l) {
  __builtin_amdgcn_global_load_lds((const __attribute__((address_space(1))) void*)g,
                                   (__attribute__((address_space(3))) void*)l, 16, 0, 0);
}

// ---------------- f32 -> bf16 convert (vectorized) ----------------
__global__ __launch_bounds__(256) void k_f32_to_bf16(const float* __restrict__ src,
                                                     u16* __restrict__ dst, int n4) {
  int i = blockIdx.x * 256 + threadIdx.x;
  if (i >= n4) return;
  float4 v = reinterpret_cast<const float4*>(src)[i];
  ushort4 o;
  o.x = f2bf(v.x); o.y = f2bf(v.y); o.z = f2bf(v.z); o.w = f2bf(v.w);
  reinterpret_cast<ushort4*>(dst)[i] = o;
}

// ---------------- RoPE cos/sin table: [S][32] float2 ----------------
__global__ __launch_bounds__(256) void k_rope_table(const int* __restrict__ pos,
                                                    float2* __restrict__ tab) {
  int idx = blockIdx.x * 256 + threadIdx.x;
  if (idx >= S_ * 32) return;
  int s = idx >> 5, i = idx & 31;
  float freq = powf(10000.0f, -(float)i * (1.0f / 32.0f));  // precise powf (error budget!)
  float ang = (float)pos[s] * freq;
  float sn, c;
  sincosf(ang, &sn, &c);
  tab[idx] = make_float2(c, sn);
}

// ---------------- RoPE apply in-place on bf16 [B*S][D], pairs within heads ----
__global__ __launch_bounds__(256) void k_rope_apply(u16* __restrict__ qk,
                                                    const float2* __restrict__ tab,
                                                    float scale) {
  int idx = blockIdx.x * 256 + threadIdx.x;     // B*S*H*32 = 4194304
  if (idx >= B_ * S_ * H_ * 32) return;
  int i = idx & 31;
  int h = (idx >> 5) & 15;
  int s = (idx >> 9) & 2047;
  int b = idx >> 20;
  float2 cs = tab[(s << 5) | i];
  size_t base = ((size_t)(b * S_ + s) << 10) + h * 64 + 2 * i;
  ushort2 xv = *reinterpret_cast<ushort2*>(qk + base);
  float x1 = bf2f(xv.x), x2 = bf2f(xv.y);
  ushort2 o;
  o.x = f2bf((x1 * cs.x - x2 * cs.y) * scale);
  o.y = f2bf((x1 * cs.y + x2 * cs.x) * scale);
  *reinterpret_cast<ushort2*>(qk + base) = o;
}

// ---------------- GEMM: C[M][N] = A[M][K] * Bw[N][K]^T  (both K-major bf16) ----
template <int OUT_BF16>
__global__ __launch_bounds__(256) void k_gemm_bt(const u16* __restrict__ A,
                                                 const u16* __restrict__ Bw,
                                                 void* __restrict__ C,
                                                 int M, int N, int K) {
  __shared__ u16 As[128 * 32];
  __shared__ u16 Bs[128 * 32];
  const int nbx = N >> 7;
  const int bx = blockIdx.x % nbx;
  const int by = blockIdx.x / nbx;
  const int m0 = by << 7, n0 = bx << 7;
  const int tid = threadIdx.x;
  const int lane = tid & 63;
  const int wv = tid >> 6;
  const int wm = (wv >> 1) << 6;
  const int wn = (wv & 1) << 6;
  const int r = lane & 15, g = lane >> 4;

  f32x4 acc[4][4] = {};

  const int o0 = tid << 4;       // byte offset in 8KB tile, issue 0
  const int o1 = o0 + 4096;      // issue 1
  const int am0 = o0 >> 6, ak0 = (o0 & 63) >> 1;
  const int am1 = o1 >> 6, ak1 = (o1 & 63) >> 1;

  for (int k0 = 0; k0 < K; k0 += 32) {
    gload_lds16(A + (size_t)(m0 + am0) * K + k0 + ak0, As + (o0 >> 1));
    gload_lds16(A + (size_t)(m0 + am1) * K + k0 + ak1, As + (o1 >> 1));
    gload_lds16(Bw + (size_t)(n0 + am0) * K + k0 + ak0, Bs + (o0 >> 1));
    gload_lds16(Bw + (size_t)(n0 + am1) * K + k0 + ak1, Bs + (o1 >> 1));
    __syncthreads();
    bf16x8 af[4], bfr[4];
#pragma unroll
    for (int i = 0; i < 4; i++)
      af[i] = *reinterpret_cast<const bf16x8*>(&As[(wm + i * 16 + r) * 32 + g * 8]);
#pragma unroll
    for (int t = 0; t < 4; t++)
      bfr[t] = *reinterpret_cast<const bf16x8*>(&Bs[(wn + t * 16 + r) * 32 + g * 8]);
#pragma unroll
    for (int i = 0; i < 4; i++)
#pragma unroll
      for (int t = 0; t < 4; t++)
        acc[i][t] = __builtin_amdgcn_mfma_f32_16x16x32_bf16(af[i], bfr[t], acc[i][t], 0, 0, 0);
    __syncthreads();
  }

#pragma unroll
  for (int i = 0; i < 4; i++) {
#pragma unroll
    for (int t = 0; t < 4; t++) {
      const int row = m0 + wm + i * 16 + g * 4;
      const int col = n0 + wn + t * 16 + r;
#pragma unroll
      for (int j = 0; j < 4; j++) {
        float v = acc[i][t][j];
        if (OUT_BF16)
          ((u16*)C)[(size_t)(row + j) * N + col] = f2bf(v);
        else
          ((float*)C)[(size_t)(row + j) * N + col] = v;
      }
    }
  }
}

// ---------------- V transpose: Vb[B*S][D] -> Vt[bh][d(64)][s(2048)] ----------
__global__ __launch_bounds__(256) void k_transpose_v(const u16* __restrict__ Vb,
                                                     u16* __restrict__ Vt) {
  __shared__ u16 tile[64][65];
  int bh = blockIdx.x >> 5;
  int st = blockIdx.x & 31;
  int b = bh >> 4, h = bh & 15;
  int s0 = st << 6;
  int tid = threadIdx.x;
#pragma unroll
  for (int rr = 0; rr < 16; rr++) {
    int idx = rr * 256 + tid;
    int sl = idx >> 6, d = idx & 63;
    tile[d][sl] = Vb[(size_t)(b * S_ + s0 + sl) * 1024 + h * 64 + d];
  }
  __syncthreads();
#pragma unroll
  for (int rr = 0; rr < 16; rr++) {
    int idx = rr * 256 + tid;
    int d = idx >> 6, sl = idx & 63;
    Vt[(size_t)(bh * 64 + d) * 2048 + s0 + sl] = tile[d][sl];
  }
}

// ---------------- Flash attention v2 (rescale bug fixed) ---------------------
// 4 waves/block, 128 q-rows/block (32 per wave), KVBLK=64 staged in LDS with
// XOR-swizzle (pre-swizzled global source, swizzled ds_read). XCD-swizzled grid.
// Q pre-scaled by 1/8. Layouts: Q,K [B*S][D] bf16 ; Vt [bh][64][2048] bf16.
__global__ __launch_bounds__(256) void k_attn2(const u16* __restrict__ Q,
                                               const u16* __restrict__ Kb,
                                               const u16* __restrict__ Vt,
                                               u16* __restrict__ O) {
  __shared__ u16 Ks[64 * 64];       // [k(64)][d(64)] swizzled
  __shared__ u16 Vs[64 * 64];       // [d(64)][kv(64)] swizzled
  __shared__ u16 Ps[4 * 32 * 64];   // per-wave [q(32)][k(64)] swizzled

  // XCD swizzle: 1024 blocks, each XCD gets 128 consecutive logical blocks
  int bid = (blockIdx.x & 7) * 128 + (blockIdx.x >> 3);
  int bh = bid >> 4;                // 0..63 (8 bh per XCD -> K/V fits its L2)
  int qb = bid & 15;
  int b = bh >> 4, h = bh & 15;
  int tid = threadIdx.x;
  int lane = tid & 63, w = tid >> 6;
  int g = lane >> 4, r = lane & 15;
  int q0 = qb << 7;
  int qw0 = q0 + w * 32;            // this wave's first q-row

  const u16* Kbase = Kb + (size_t)(b * S_) * 1024 + h * 64;
  const u16* Vbase = Vt + (size_t)bh * 64 * 2048;

  // Q fragments: 2 q-tiles x 2 k-chunks
  bf16x8 qf[2][2];
#pragma unroll
  for (int qt = 0; qt < 2; qt++) {
    const u16* qrow = Q + (size_t)(b * S_ + qw0 + qt * 16 + r) * 1024 + h * 64;
    qf[qt][0] = *reinterpret_cast<const bf16x8*>(qrow + g * 8);
    qf[qt][1] = *reinterpret_cast<const bf16x8*>(qrow + 32 + g * 8);
  }

  f32x4 o_acc[2][4] = {};
  float m_run[2][4], l_run[2][4];
#pragma unroll
  for (int qt = 0; qt < 2; qt++)
#pragma unroll
    for (int j = 0; j < 4; j++) { m_run[qt][j] = -1e30f; l_run[qt][j] = 0.f; }

  // staging: thread tid covers LDS row srow (and srow+32), 16B chunk (tid&7)
  const int srow = tid >> 3;
  const int ssw = (srow & 7) * 8;                 // same for srow+32
  const int scol = ((tid & 7) * 8) ^ ssw;         // pre-swizzled source col (u16)
  const int rsw = (r & 7) * 8;                    // read-side swizzle (u16)

  const int kend = q0 + 128;
  for (int k0 = 0; k0 < kend; k0 += 64) {
    gload_lds16(Kbase + (size_t)(k0 + srow) * 1024 + scol, Ks + tid * 8);
    gload_lds16(Kbase + (size_t)(k0 + srow + 32) * 1024 + scol, Ks + tid * 8 + 2048);
    gload_lds16(Vbase + (size_t)srow * 2048 + k0 + scol, Vs + tid * 8);
    gload_lds16(Vbase + (size_t)(srow + 32) * 2048 + k0 + scol, Vs + tid * 8 + 2048);
    __syncthreads();

    if (k0 <= qw0 + 31) {   // wave-uniform: this wave's rows need this k-tile
#pragma unroll
      for (int qt = 0; qt < 2; qt++) {
        const int row0 = qw0 + qt * 16;
        // ---- QK^T: 16 q-rows x 64 k-cols ----
        float sv[4][4];
#pragma unroll
        for (int kt = 0; kt < 4; kt++) {
          const int krow = kt * 16 + r;
          bf16x8 kf0 = *reinterpret_cast<const bf16x8*>(&Ks[krow * 64 + ((g * 8) ^ rsw)]);
          bf16x8 kf1 = *reinterpret_cast<const bf16x8*>(&Ks[krow * 64 + ((32 + g * 8) ^ rsw)]);
          f32x4 sa = {};
          sa = __builtin_amdgcn_mfma_f32_16x16x32_bf16(qf[qt][0], kf0, sa, 0, 0, 0);
          sa = __builtin_amdgcn_mfma_f32_16x16x32_bf16(qf[qt][1], kf1, sa, 0, 0, 0);
#pragma unroll
          for (int j = 0; j < 4; j++) sv[kt][j] = sa[j];
        }
        // ---- causal mask ----
        if (k0 + 63 > row0) {
#pragma unroll
          for (int kt = 0; kt < 4; kt++) {
            const int col = k0 + kt * 16 + r;
#pragma unroll
            for (int j = 0; j < 4; j++)
              if (col > row0 + g * 4 + j) sv[kt][j] = -1e30f;
          }
        }
        // ---- online softmax (16-lane groups) + P write ----
#pragma unroll
        for (int j = 0; j < 4; j++) {
          float t = fmaxf(fmaxf(sv[0][j], sv[1][j]), fmaxf(sv[2][j], sv[3][j]));
#pragma unroll
          for (int off = 1; off < 16; off <<= 1) t = fmaxf(t, __shfl_xor(t, off));
          float mnew = fmaxf(m_run[qt][j], t);
          float sc = __expf(m_run[qt][j] - mnew);
          m_run[qt][j] = mnew;
          float pp[4], s = 0.f;
#pragma unroll
          for (int kt = 0; kt < 4; kt++) { pp[kt] = __expf(sv[kt][j] - mnew); s += pp[kt]; }
#pragma unroll
          for (int off = 1; off < 16; off <<= 1) s += __shfl_xor(s, off);
          l_run[qt][j] = l_run[qt][j] * sc + s;
          // rescale: ONLY accumulator element j (output row g*4+j). The
          // whole-vector `o_acc[qt][dt] *= sc` was round-2's absmax bug.
#pragma unroll
          for (int dt = 0; dt < 4; dt++) o_acc[qt][dt][j] *= sc;
          const int prow = qt * 16 + g * 4 + j;
          const int psw = (prow & 7) * 8;
          u16* pb = Ps + w * 2048 + prow * 64;
#pragma unroll
          for (int kt = 0; kt < 4; kt++) pb[(kt * 16 + r) ^ psw] = f2bf(pp[kt]);
        }
      }
      // wave-internal: P writes must land before reads
      asm volatile("s_waitcnt lgkmcnt(0)" ::: "memory");
      // ---- PV ----
#pragma unroll
      for (int kc = 0; kc < 2; kc++) {
        const int cb = (kc * 32 + g * 8);
        bf16x8 pf0 = *reinterpret_cast<const bf16x8*>(&Ps[w * 2048 + r * 64 + (cb ^ rsw)]);
        bf16x8 pf1 = *reinterpret_cast<const bf16x8*>(&Ps[w * 2048 + (16 + r) * 64 + (cb ^ rsw)]);
#pragma unroll
        for (int dt = 0; dt < 4; dt++) {
          bf16x8 vf = *reinterpret_cast<const bf16x8*>(&Vs[(dt * 16 + r) * 64 + (cb ^ rsw)]);
          o_acc[0][dt] = __builtin_amdgcn_mfma_f32_16x16x32_bf16(pf0, vf, o_acc[0][dt], 0, 0, 0);
          o_acc[1][dt] = __builtin_amdgcn_mfma_f32_16x16x32_bf16(pf1, vf, o_acc[1][dt], 0, 0, 0);
        }
      }
    }
    __syncthreads();
  }

  // epilogue
#pragma unroll
  for (int qt = 0; qt < 2; qt++) {
    u16* orow = O + (size_t)(b * S_ + qw0 + qt * 16) * 1024 + h * 64;
#pragma unroll
    for (int dt = 0; dt < 4; dt++)
#pragma unroll
      for (int j = 0; j < 4; j++) {
        float v = o_acc[qt][dt][j] / l_run[qt][j];
        orow[(size_t)(g * 4 + j) * 1024 + dt * 16 + r] = f2bf(v);
      }
  }
}

// ---------------- host side ----------------
extern "C" void kernel_launch(void* const* d_in, const int* in_sizes, int n_in,
                              void* d_out, int out_size, void* d_ws, size_t ws_size,
                              hipStream_t stream) {
  const float* x  = (const float*)d_in[0];
  const int*   pos = (const int*)d_in[1];
  const float* Wq = (const float*)d_in[2];
  const float* Wk = (const float*)d_in[3];
  const float* Wv = (const float*)d_in[4];
  const float* Wo = (const float*)d_in[5];
  float* out = (float*)d_out;

  char* ws = (char*)d_ws;
  size_t off = 0;
  auto alloc = [&](size_t bytes) {
    void* p = ws + off;
    off += (bytes + 255) & ~(size_t)255;
    return p;
  };
  const size_t XB = (size_t)8192 * 1024 * 2;  // bf16 [B*S][D]
  u16* xb  = (u16*)alloc(XB);
  u16* wqb = (u16*)alloc((size_t)1024 * 1024 * 2);
  u16* wkb = (u16*)alloc((size_t)1024 * 1024 * 2);
  u16* wvb = (u16*)alloc((size_t)1024 * 1024 * 2);
  u16* wob = (u16*)alloc((size_t)1024 * 1024 * 2);
  u16* qb  = (u16*)alloc(XB);
  u16* kb  = (u16*)alloc(XB);
  u16* vb  = (u16*)alloc(XB);
  u16* vt  = (u16*)alloc(XB);
  float2* tab = (float2*)alloc((size_t)2048 * 32 * sizeof(float2));
  u16* ob = vb;  // alias: vb dead after transpose

  // converts
  k_f32_to_bf16<<<8192, 256, 0, stream>>>(x, xb, 2097152);
  k_f32_to_bf16<<<1024, 256, 0, stream>>>(Wq, wqb, 262144);
  k_f32_to_bf16<<<1024, 256, 0, stream>>>(Wk, wkb, 262144);
  k_f32_to_bf16<<<1024, 256, 0, stream>>>(Wv, wvb, 262144);
  k_f32_to_bf16<<<1024, 256, 0, stream>>>(Wo, wob, 262144);
  k_rope_table<<<256, 256, 0, stream>>>(pos, tab);

  // QKV projections (M=8192, N=1024, K=1024)
  k_gemm_bt<1><<<512, 256, 0, stream>>>(xb, wqb, qb, 8192, 1024, 1024);
  k_gemm_bt<1><<<512, 256, 0, stream>>>(xb, wkb, kb, 8192, 1024, 1024);
  k_gemm_bt<1><<<512, 256, 0, stream>>>(xb, wvb, vb, 8192, 1024, 1024);

  // RoPE (Q also gets the 1/sqrt(dk)=0.125 scale folded in)
  k_rope_apply<<<16384, 256, 0, stream>>>(qb, tab, 0.125f);
  k_rope_apply<<<16384, 256, 0, stream>>>(kb, tab, 1.0f);

  // V transpose for PV fragment loads
  k_transpose_v<<<2048, 256, 0, stream>>>(vb, vt);

  // flash attention v2: 64 (b,h) x 16 q-blocks of 128 rows
  k_attn2<<<1024, 256, 0, stream>>>(qb, kb, vt, ob);

  // output projection -> f32 out
  k_gemm_bt<0><<<512, 256, 0, stream>>>(ob, wob, out, 8192, 1024, 1024);
}

// Round 4
// 243.974 us; speedup vs baseline: 2.0596x; 1.4381x over previous
//
#include <hip/hip_runtime.h>

typedef unsigned short u16;
typedef __bf16 bf16x8 __attribute__((ext_vector_type(8)));
typedef float f32x4 __attribute__((ext_vector_type(4)));

#define B_ 4
#define S_ 2048
#define D_ 1024
#define H_ 16

__device__ inline u16 f2bf(float f) {
  unsigned u = __float_as_uint(f);
  u = u + 0x7fffu + ((u >> 16) & 1u);
  return (u16)(u >> 16);
}
__device__ inline u16 f2bf_hw(float f) {
  __bf16 b = (__bf16)f;
  return __builtin_bit_cast(u16, b);
}
__device__ inline float bf2f(u16 h) {
  return __uint_as_float(((unsigned)h) << 16);
}
__device__ inline void gload_lds16(const u16* g, u16* l) {
  __builtin_amdgcn_global_load_lds((const __attribute__((address_space(1))) void*)g,
                                   (__attribute__((address_space(3))) void*)l, 16, 0, 0);
}

// ---------------- f32 -> bf16 convert (vectorized) ----------------
__global__ __launch_bounds__(256) void k_f32_to_bf16(const float* __restrict__ src,
                                                     u16* __restrict__ dst, int n4) {
  int i = blockIdx.x * 256 + threadIdx.x;
  if (i >= n4) return;
  float4 v = reinterpret_cast<const float4*>(src)[i];
  ushort4 o;
  o.x = f2bf(v.x); o.y = f2bf(v.y); o.z = f2bf(v.z); o.w = f2bf(v.w);
  reinterpret_cast<ushort4*>(dst)[i] = o;
}

// ---------------- RoPE cos/sin table: [S][32] float2 ----------------
__global__ __launch_bounds__(256) void k_rope_table(const int* __restrict__ pos,
                                                    float2* __restrict__ tab) {
  int idx = blockIdx.x * 256 + threadIdx.x;
  if (idx >= S_ * 32) return;
  int s = idx >> 5, i = idx & 31;
  float freq = powf(10000.0f, -(float)i * (1.0f / 32.0f));  // precise powf (error budget!)
  float ang = (float)pos[s] * freq;
  float sn, c;
  sincosf(ang, &sn, &c);
  tab[idx] = make_float2(c, sn);
}

// ---------------- RoPE apply in-place on bf16 [B*S][D], pairs within heads ----
__global__ __launch_bounds__(256) void k_rope_apply(u16* __restrict__ qk,
                                                    const float2* __restrict__ tab,
                                                    float scale) {
  int idx = blockIdx.x * 256 + threadIdx.x;     // B*S*H*32 = 4194304
  if (idx >= B_ * S_ * H_ * 32) return;
  int i = idx & 31;
  int h = (idx >> 5) & 15;
  int s = (idx >> 9) & 2047;
  int b = idx >> 20;
  float2 cs = tab[(s << 5) | i];
  size_t base = ((size_t)(b * S_ + s) << 10) + h * 64 + 2 * i;
  ushort2 xv = *reinterpret_cast<ushort2*>(qk + base);
  float x1 = bf2f(xv.x), x2 = bf2f(xv.y);
  ushort2 o;
  o.x = f2bf((x1 * cs.x - x2 * cs.y) * scale);
  o.y = f2bf((x1 * cs.y + x2 * cs.x) * scale);
  *reinterpret_cast<ushort2*>(qk + base) = o;
}

// ---------------- GEMM: C[M][N] = A[M][K] * Bw[N][K]^T  (both K-major bf16) ----
// m97 structure + XCD-aware block swizzle (grid % 8 == 0 always here).
template <int OUT_BF16>
__global__ __launch_bounds__(256) void k_gemm_bt(const u16* __restrict__ A,
                                                 const u16* __restrict__ Bw,
                                                 void* __restrict__ C,
                                                 int M, int N, int K) {
  __shared__ u16 As[128 * 32];
  __shared__ u16 Bs[128 * 32];
  const int nbx = N >> 7;
  const int swz = (blockIdx.x & 7) * (gridDim.x >> 3) + (blockIdx.x >> 3);
  const int bx = swz % nbx;
  const int by = swz / nbx;
  const int m0 = by << 7, n0 = bx << 7;
  const int tid = threadIdx.x;
  const int lane = tid & 63;
  const int wv = tid >> 6;
  const int wm = (wv >> 1) << 6;
  const int wn = (wv & 1) << 6;
  const int r = lane & 15, g = lane >> 4;

  f32x4 acc[4][4] = {};

  const int o0 = tid << 4;       // byte offset in 8KB tile, issue 0
  const int o1 = o0 + 4096;      // issue 1
  const int am0 = o0 >> 6, ak0 = (o0 & 63) >> 1;
  const int am1 = o1 >> 6, ak1 = (o1 & 63) >> 1;

  for (int k0 = 0; k0 < K; k0 += 32) {
    gload_lds16(A + (size_t)(m0 + am0) * K + k0 + ak0, As + (o0 >> 1));
    gload_lds16(A + (size_t)(m0 + am1) * K + k0 + ak1, As + (o1 >> 1));
    gload_lds16(Bw + (size_t)(n0 + am0) * K + k0 + ak0, Bs + (o0 >> 1));
    gload_lds16(Bw + (size_t)(n0 + am1) * K + k0 + ak1, Bs + (o1 >> 1));
    __syncthreads();
    bf16x8 af[4], bfr[4];
#pragma unroll
    for (int i = 0; i < 4; i++)
      af[i] = *reinterpret_cast<const bf16x8*>(&As[(wm + i * 16 + r) * 32 + g * 8]);
#pragma unroll
    for (int t = 0; t < 4; t++)
      bfr[t] = *reinterpret_cast<const bf16x8*>(&Bs[(wn + t * 16 + r) * 32 + g * 8]);
#pragma unroll
    for (int i = 0; i < 4; i++)
#pragma unroll
      for (int t = 0; t < 4; t++)
        acc[i][t] = __builtin_amdgcn_mfma_f32_16x16x32_bf16(af[i], bfr[t], acc[i][t], 0, 0, 0);
    __syncthreads();
  }

#pragma unroll
  for (int i = 0; i < 4; i++) {
#pragma unroll
    for (int t = 0; t < 4; t++) {
      const int row = m0 + wm + i * 16 + g * 4;
      const int col = n0 + wn + t * 16 + r;
#pragma unroll
      for (int j = 0; j < 4; j++) {
        float v = acc[i][t][j];
        if (OUT_BF16)
          ((u16*)C)[(size_t)(row + j) * N + col] = f2bf(v);
        else
          ((float*)C)[(size_t)(row + j) * N + col] = v;
      }
    }
  }
}

// ---------------- V transpose: Vb[B*S][D] -> Vt[bh][d(64)][s(2048)] ----------
__global__ __launch_bounds__(256) void k_transpose_v(const u16* __restrict__ Vb,
                                                     u16* __restrict__ Vt) {
  __shared__ u16 tile[64][65];
  int bh = blockIdx.x >> 5;
  int st = blockIdx.x & 31;
  int b = bh >> 4, h = bh & 15;
  int s0 = st << 6;
  int tid = threadIdx.x;
#pragma unroll
  for (int rr = 0; rr < 16; rr++) {
    int idx = rr * 256 + tid;
    int sl = idx >> 6, d = idx & 63;
    tile[d][sl] = Vb[(size_t)(b * S_ + s0 + sl) * 1024 + h * 64 + d];
  }
  __syncthreads();
#pragma unroll
  for (int rr = 0; rr < 16; rr++) {
    int idx = rr * 256 + tid;
    int d = idx >> 6, sl = idx & 63;
    Vt[(size_t)(bh * 64 + d) * 2048 + s0 + sl] = tile[d][sl];
  }
}

// ---------------- Flash attention v3 ----------------------------------------
// Triangle-folded: block handles q-tile pair (qp, 31-qp) of 64 rows each in two
// phases -> uniform 33 k-iterations for every block. 4 waves x 16 q-rows/phase.
// Swapped QK^T: mfma(K,Q) = S^T, so each lane owns q-row (lane&15): row reduce
// is in-lane + 2 shuffles; P written as packed b64 swizzled stores.
// Q pre-scaled by 1/8. Layouts: Q,K [B*S][D] bf16 ; Vt [bh][64][2048] bf16.
__global__ __launch_bounds__(256) void k_attn3(const u16* __restrict__ Q,
                                               const u16* __restrict__ Kb,
                                               const u16* __restrict__ Vt,
                                               u16* __restrict__ O) {
  __shared__ u16 Ks[64 * 64];       // [k(64)][d(64)] swizzled
  __shared__ u16 Vs[64 * 64];       // [d(64)][kv(64)] swizzled
  __shared__ u16 Ps[4 * 16 * 64];   // per-wave [q(16)][k(64)] swizzled

  // XCD swizzle: 1024 blocks -> each XCD owns 8 (b,h) pairs (K+V = 4MB = L2)
  int bid = (blockIdx.x & 7) * 128 + (blockIdx.x >> 3);
  int bh = bid >> 4;
  int qp = bid & 15;
  int b = bh >> 4, h = bh & 15;
  int tid = threadIdx.x;
  int lane = tid & 63, w = tid >> 6;
  int g = lane >> 4, r = lane & 15;

  const u16* Kbase = Kb + (size_t)(b * S_) * 1024 + h * 64;
  const u16* Vbase = Vt + (size_t)bh * 64 * 2048;

  // staging: thread tid covers LDS rows srow, srow+32; 16B chunk (tid&7)
  const int srow = tid >> 3;
  const int ssw = (srow & 7) * 8;
  const int scol = ((tid & 7) * 8) ^ ssw;         // pre-swizzled source col (u16)
  const int rsw = (r & 7) * 8;                    // read/P-write swizzle (u16)

  u16* pbase = Ps + (w << 10) + (r << 6);         // this lane's P row (q = r)

  for (int ph = 0; ph < 2; ph++) {
    const int qtile = ph ? (31 - qp) : qp;
    const int qbase = qtile << 6;
    const int qrow0 = qbase + (w << 4);           // wave's first q-row

    const u16* qrow = Q + (size_t)(b * S_ + qrow0 + r) * 1024 + h * 64;
    bf16x8 qf0 = *reinterpret_cast<const bf16x8*>(qrow + g * 8);
    bf16x8 qf1 = *reinterpret_cast<const bf16x8*>(qrow + 32 + g * 8);

    f32x4 o_acc[4] = {};
    float m_run = -1e30f, l_run = 0.f;

    for (int k0 = 0; k0 <= qbase; k0 += 64) {
      gload_lds16(Kbase + (size_t)(k0 + srow) * 1024 + scol, Ks + tid * 8);
      gload_lds16(Kbase + (size_t)(k0 + srow + 32) * 1024 + scol, Ks + tid * 8 + 2048);
      gload_lds16(Vbase + (size_t)srow * 2048 + k0 + scol, Vs + tid * 8);
      gload_lds16(Vbase + (size_t)(srow + 32) * 2048 + k0 + scol, Vs + tid * 8 + 2048);
      __syncthreads();

      // ---- swapped QK^T: lane (r,g) gets S[k=k0+kt*16+g*4+j][q=qrow0+r] ----
      float sv[4][4];
#pragma unroll
      for (int kt = 0; kt < 4; kt++)
#pragma unroll
        for (int j = 0; j < 4; j++) sv[kt][j] = -1e30f;

      const int rem = (qrow0 + 15 - k0) >> 4;     // wave-uniform
      const int ktlim = rem >= 3 ? 4 : rem + 1;
      const bool needmask = (k0 == qbase);        // only diagonal tile

#pragma unroll
      for (int kt = 0; kt < 4; kt++) {
        if (kt < ktlim) {
          const int krow = kt * 16 + r;
          bf16x8 kf0 = *reinterpret_cast<const bf16x8*>(&Ks[krow * 64 + ((g * 8) ^ rsw)]);
          bf16x8 kf1 = *reinterpret_cast<const bf16x8*>(&Ks[krow * 64 + ((32 + g * 8) ^ rsw)]);
          f32x4 sa = {};
          sa = __builtin_amdgcn_mfma_f32_16x16x32_bf16(kf0, qf0, sa, 0, 0, 0);
          sa = __builtin_amdgcn_mfma_f32_16x16x32_bf16(kf1, qf1, sa, 0, 0, 0);
#pragma unroll
          for (int j = 0; j < 4; j++) sv[kt][j] = sa[j];
        }
      }

      if (needmask) {
        const int qg = qrow0 + r;
#pragma unroll
        for (int kt = 0; kt < 4; kt++)
#pragma unroll
          for (int j = 0; j < 4; j++)
            if (k0 + kt * 16 + g * 4 + j > qg) sv[kt][j] = -1e30f;
      }

      // ---- online softmax: in-lane tree + 2 shuffles (lane owns q = r) ----
      float mx = -1e30f;
#pragma unroll
      for (int kt = 0; kt < 4; kt++)
#pragma unroll
        for (int j = 0; j < 4; j++) mx = fmaxf(mx, sv[kt][j]);
      mx = fmaxf(mx, __shfl_xor(mx, 16));
      mx = fmaxf(mx, __shfl_xor(mx, 32));
      const float mnew = fmaxf(m_run, mx);
      const float sc = __expf(m_run - mnew);
      m_run = mnew;
      float pp[4][4], psum = 0.f;
#pragma unroll
      for (int kt = 0; kt < 4; kt++)
#pragma unroll
        for (int j = 0; j < 4; j++) {
          pp[kt][j] = __expf(sv[kt][j] - mnew);
          psum += pp[kt][j];
        }
      psum += __shfl_xor(psum, 16);
      psum += __shfl_xor(psum, 32);
      l_run = l_run * sc + psum;

      // rescale o_acc: element j is output row q = g*4+j -> fetch its sc
#pragma unroll
      for (int j = 0; j < 4; j++) {
        const float scq = __shfl(sc, 4 * g + j);
#pragma unroll
        for (int dt = 0; dt < 4; dt++) o_acc[dt][j] *= scq;
      }

      // P pack + swizzled b64 writes: row q = r, cols kt*16+g*4..+3
#pragma unroll
      for (int kt = 0; kt < 4; kt++) {
        ushort4 pw;
        pw.x = f2bf_hw(pp[kt][0]); pw.y = f2bf_hw(pp[kt][1]);
        pw.z = f2bf_hw(pp[kt][2]); pw.w = f2bf_hw(pp[kt][3]);
        *reinterpret_cast<ushort4*>(pbase + ((kt * 16 + g * 4) ^ rsw)) = pw;
      }
      asm volatile("s_waitcnt lgkmcnt(0)" ::: "memory");

      // ---- PV: A = P (q rows = lane&15), B = V^T ----
#pragma unroll
      for (int kc = 0; kc < 2; kc++) {
        const int cb = (kc * 32 + g * 8);
        bf16x8 pf = *reinterpret_cast<const bf16x8*>(pbase + (cb ^ rsw));
#pragma unroll
        for (int dt = 0; dt < 4; dt++) {
          bf16x8 vf = *reinterpret_cast<const bf16x8*>(&Vs[(dt * 16 + r) * 64 + (cb ^ rsw)]);
          o_acc[dt] = __builtin_amdgcn_mfma_f32_16x16x32_bf16(pf, vf, o_acc[dt], 0, 0, 0);
        }
      }
      __syncthreads();
    }

    // epilogue: o_acc[dt][j] = O[q = qrow0+g*4+j][d = dt*16+r]
    u16* orow = O + (size_t)(b * S_ + qrow0) * 1024 + h * 64;
#pragma unroll
    for (int j = 0; j < 4; j++) {
      const float ln = __shfl(l_run, 4 * g + j);
#pragma unroll
      for (int dt = 0; dt < 4; dt++)
        orow[(size_t)(g * 4 + j) * 1024 + dt * 16 + r] = f2bf(o_acc[dt][j] / ln);
    }
  }
}

// ---------------- host side ----------------
extern "C" void kernel_launch(void* const* d_in, const int* in_sizes, int n_in,
                              void* d_out, int out_size, void* d_ws, size_t ws_size,
                              hipStream_t stream) {
  const float* x  = (const float*)d_in[0];
  const int*   pos = (const int*)d_in[1];
  const float* Wq = (const float*)d_in[2];
  const float* Wk = (const float*)d_in[3];
  const float* Wv = (const float*)d_in[4];
  const float* Wo = (const float*)d_in[5];
  float* out = (float*)d_out;

  char* ws = (char*)d_ws;
  size_t off = 0;
  auto alloc = [&](size_t bytes) {
    void* p = ws + off;
    off += (bytes + 255) & ~(size_t)255;
    return p;
  };
  const size_t XB = (size_t)8192 * 1024 * 2;  // bf16 [B*S][D]
  u16* xb  = (u16*)alloc(XB);
  u16* wqb = (u16*)alloc((size_t)1024 * 1024 * 2);
  u16* wkb = (u16*)alloc((size_t)1024 * 1024 * 2);
  u16* wvb = (u16*)alloc((size_t)1024 * 1024 * 2);
  u16* wob = (u16*)alloc((size_t)1024 * 1024 * 2);
  u16* qb  = (u16*)alloc(XB);
  u16* kb  = (u16*)alloc(XB);
  u16* vb  = (u16*)alloc(XB);
  u16* vt  = (u16*)alloc(XB);
  float2* tab = (float2*)alloc((size_t)2048 * 32 * sizeof(float2));
  u16* ob = vb;  // alias: vb dead after transpose

  // converts
  k_f32_to_bf16<<<8192, 256, 0, stream>>>(x, xb, 2097152);
  k_f32_to_bf16<<<1024, 256, 0, stream>>>(Wq, wqb, 262144);
  k_f32_to_bf16<<<1024, 256, 0, stream>>>(Wk, wkb, 262144);
  k_f32_to_bf16<<<1024, 256, 0, stream>>>(Wv, wvb, 262144);
  k_f32_to_bf16<<<1024, 256, 0, stream>>>(Wo, wob, 262144);
  k_rope_table<<<256, 256, 0, stream>>>(pos, tab);

  // QKV projections (M=8192, N=1024, K=1024)
  k_gemm_bt<1><<<512, 256, 0, stream>>>(xb, wqb, qb, 8192, 1024, 1024);
  k_gemm_bt<1><<<512, 256, 0, stream>>>(xb, wkb, kb, 8192, 1024, 1024);
  k_gemm_bt<1><<<512, 256, 0, stream>>>(xb, wvb, vb, 8192, 1024, 1024);

  // RoPE (Q also gets the 1/sqrt(dk)=0.125 scale folded in)
  k_rope_apply<<<16384, 256, 0, stream>>>(qb, tab, 0.125f);
  k_rope_apply<<<16384, 256, 0, stream>>>(kb, tab, 1.0f);

  // V transpose for PV fragment loads
  k_transpose_v<<<2048, 256, 0, stream>>>(vb, vt);

  // flash attention v3: 64 (b,h) x 16 folded q-tile pairs
  k_attn3<<<1024, 256, 0, stream>>>(qb, kb, vt, ob);

  // output projection -> f32 out
  k_gemm_bt<0><<<512, 256, 0, stream>>>(ob, wob, out, 8192, 1024, 1024);
}

// Round 5
// 229.015 us; speedup vs baseline: 2.1941x; 1.0653x over previous
//
#include <hip/hip_runtime.h>

typedef unsigned short u16;
typedef __bf16 bf16x8 __attribute__((ext_vector_type(8)));
typedef float f32x4 __attribute__((ext_vector_type(4)));

#define B_ 4
#define S_ 2048
#define D_ 1024
#define H_ 16
#define LOG2E 1.44269504f

__device__ inline u16 f2bf(float f) {
  unsigned u = __float_as_uint(f);
  u = u + 0x7fffu + ((u >> 16) & 1u);
  return (u16)(u >> 16);
}
__device__ inline u16 f2bf_hw(float f) {
  __bf16 b = (__bf16)f;
  return __builtin_bit_cast(u16, b);
}
__device__ inline float bf2f(u16 h) {
  return __uint_as_float(((unsigned)h) << 16);
}
__device__ inline void gload_lds16(const u16* g, u16* l) {
  __builtin_amdgcn_global_load_lds((const __attribute__((address_space(1))) void*)g,
                                   (__attribute__((address_space(3))) void*)l, 16, 0, 0);
}

// ---------------- f32 -> bf16 convert (vectorized) ----------------
__global__ __launch_bounds__(256) void k_f32_to_bf16(const float* __restrict__ src,
                                                     u16* __restrict__ dst, int n4) {
  int i = blockIdx.x * 256 + threadIdx.x;
  if (i >= n4) return;
  float4 v = reinterpret_cast<const float4*>(src)[i];
  ushort4 o;
  o.x = f2bf(v.x); o.y = f2bf(v.y); o.z = f2bf(v.z); o.w = f2bf(v.w);
  reinterpret_cast<ushort4*>(dst)[i] = o;
}

// ---------------- RoPE cos/sin table: [S][32] float2 ----------------
__global__ __launch_bounds__(256) void k_rope_table(const int* __restrict__ pos,
                                                    float2* __restrict__ tab) {
  int idx = blockIdx.x * 256 + threadIdx.x;
  if (idx >= S_ * 32) return;
  int s = idx >> 5, i = idx & 31;
  float freq = powf(10000.0f, -(float)i * (1.0f / 32.0f));  // precise powf (error budget!)
  float ang = (float)pos[s] * freq;
  float sn, c;
  sincosf(ang, &sn, &c);
  tab[idx] = make_float2(c, sn);
}

// ---------------- RoPE apply in-place on bf16 [B*S][D], pairs within heads ----
__global__ __launch_bounds__(256) void k_rope_apply(u16* __restrict__ qk,
                                                    const float2* __restrict__ tab,
                                                    float scale) {
  int idx = blockIdx.x * 256 + threadIdx.x;     // B*S*H*32 = 4194304
  if (idx >= B_ * S_ * H_ * 32) return;
  int i = idx & 31;
  int h = (idx >> 5) & 15;
  int s = (idx >> 9) & 2047;
  int b = idx >> 20;
  float2 cs = tab[(s << 5) | i];
  size_t base = ((size_t)(b * S_ + s) << 10) + h * 64 + 2 * i;
  ushort2 xv = *reinterpret_cast<ushort2*>(qk + base);
  float x1 = bf2f(xv.x), x2 = bf2f(xv.y);
  ushort2 o;
  o.x = f2bf((x1 * cs.x - x2 * cs.y) * scale);
  o.y = f2bf((x1 * cs.y + x2 * cs.x) * scale);
  *reinterpret_cast<ushort2*>(qk + base) = o;
}

// ---------------- Fused QKV GEMM ---------------------------------------------
// Ccat picks q/k/v buffer per 128-col tile; Wcat = [3072][1024] (wq|wk|wv,
// contiguous in ws). M=8192, Ncat=3072, K=1024. 1536 blocks, XCD-swizzled.
__global__ __launch_bounds__(256) void k_gemm_qkv(const u16* __restrict__ A,
                                                  const u16* __restrict__ Bcat,
                                                  u16* __restrict__ Ccat) {
  __shared__ u16 As[128 * 32];
  __shared__ u16 Bs[128 * 32];
  const int K = 1024;
  const int swz = (blockIdx.x & 7) * 192 + (blockIdx.x >> 3);
  const int bx = swz % 24;
  const int by = swz / 24;
  const int m0 = by << 7, n0 = bx << 7;
  const int tid = threadIdx.x;
  const int lane = tid & 63;
  const int wv = tid >> 6;
  const int wm = (wv >> 1) << 6;
  const int wn = (wv & 1) << 6;
  const int r = lane & 15, g = lane >> 4;

  f32x4 acc[4][4] = {};

  const int o0 = tid << 4;
  const int o1 = o0 + 4096;
  const int am0 = o0 >> 6, ak0 = (o0 & 63) >> 1;
  const int am1 = o1 >> 6, ak1 = (o1 & 63) >> 1;

  for (int k0 = 0; k0 < K; k0 += 32) {
    gload_lds16(A + (size_t)(m0 + am0) * K + k0 + ak0, As + (o0 >> 1));
    gload_lds16(A + (size_t)(m0 + am1) * K + k0 + ak1, As + (o1 >> 1));
    gload_lds16(Bcat + (size_t)(n0 + am0) * K + k0 + ak0, Bs + (o0 >> 1));
    gload_lds16(Bcat + (size_t)(n0 + am1) * K + k0 + ak1, Bs + (o1 >> 1));
    __syncthreads();
    bf16x8 af[4], bfr[4];
#pragma unroll
    for (int i = 0; i < 4; i++)
      af[i] = *reinterpret_cast<const bf16x8*>(&As[(wm + i * 16 + r) * 32 + g * 8]);
#pragma unroll
    for (int t = 0; t < 4; t++)
      bfr[t] = *reinterpret_cast<const bf16x8*>(&Bs[(wn + t * 16 + r) * 32 + g * 8]);
#pragma unroll
    for (int i = 0; i < 4; i++)
#pragma unroll
      for (int t = 0; t < 4; t++)
        acc[i][t] = __builtin_amdgcn_mfma_f32_16x16x32_bf16(af[i], bfr[t], acc[i][t], 0, 0, 0);
    __syncthreads();
  }

  u16* Cb = Ccat + (size_t)(n0 >> 10) * (8192 * 1024);
  const int c0 = n0 & 1023;
#pragma unroll
  for (int i = 0; i < 4; i++) {
#pragma unroll
    for (int t = 0; t < 4; t++) {
      const int row = m0 + wm + i * 16 + g * 4;
      const int col = c0 + wn + t * 16 + r;
#pragma unroll
      for (int j = 0; j < 4; j++)
        Cb[(size_t)(row + j) * 1024 + col] = f2bf(acc[i][t][j]);
    }
  }
}

// ---------------- GEMM: C[M][N] = A[M][K] * Bw[N][K]^T  (f32 out, for Wo) ----
__global__ __launch_bounds__(256) void k_gemm_bt(const u16* __restrict__ A,
                                                 const u16* __restrict__ Bw,
                                                 float* __restrict__ C,
                                                 int M, int N, int K) {
  __shared__ u16 As[128 * 32];
  __shared__ u16 Bs[128 * 32];
  const int nbx = N >> 7;
  const int swz = (blockIdx.x & 7) * (gridDim.x >> 3) + (blockIdx.x >> 3);
  const int bx = swz % nbx;
  const int by = swz / nbx;
  const int m0 = by << 7, n0 = bx << 7;
  const int tid = threadIdx.x;
  const int lane = tid & 63;
  const int wv = tid >> 6;
  const int wm = (wv >> 1) << 6;
  const int wn = (wv & 1) << 6;
  const int r = lane & 15, g = lane >> 4;

  f32x4 acc[4][4] = {};

  const int o0 = tid << 4;
  const int o1 = o0 + 4096;
  const int am0 = o0 >> 6, ak0 = (o0 & 63) >> 1;
  const int am1 = o1 >> 6, ak1 = (o1 & 63) >> 1;

  for (int k0 = 0; k0 < K; k0 += 32) {
    gload_lds16(A + (size_t)(m0 + am0) * K + k0 + ak0, As + (o0 >> 1));
    gload_lds16(A + (size_t)(m0 + am1) * K + k0 + ak1, As + (o1 >> 1));
    gload_lds16(Bw + (size_t)(n0 + am0) * K + k0 + ak0, Bs + (o0 >> 1));
    gload_lds16(Bw + (size_t)(n0 + am1) * K + k0 + ak1, Bs + (o1 >> 1));
    __syncthreads();
    bf16x8 af[4], bfr[4];
#pragma unroll
    for (int i = 0; i < 4; i++)
      af[i] = *reinterpret_cast<const bf16x8*>(&As[(wm + i * 16 + r) * 32 + g * 8]);
#pragma unroll
    for (int t = 0; t < 4; t++)
      bfr[t] = *reinterpret_cast<const bf16x8*>(&Bs[(wn + t * 16 + r) * 32 + g * 8]);
#pragma unroll
    for (int i = 0; i < 4; i++)
#pragma unroll
      for (int t = 0; t < 4; t++)
        acc[i][t] = __builtin_amdgcn_mfma_f32_16x16x32_bf16(af[i], bfr[t], acc[i][t], 0, 0, 0);
    __syncthreads();
  }

#pragma unroll
  for (int i = 0; i < 4; i++) {
#pragma unroll
    for (int t = 0; t < 4; t++) {
      const int row = m0 + wm + i * 16 + g * 4;
      const int col = n0 + wn + t * 16 + r;
#pragma unroll
      for (int j = 0; j < 4; j++)
        C[(size_t)(row + j) * N + col] = acc[i][t][j];
    }
  }
}

// ---------------- V transpose: Vb[B*S][D] -> Vt[bh][d(64)][s(2048)] ----------
__global__ __launch_bounds__(256) void k_transpose_v(const u16* __restrict__ Vb,
                                                     u16* __restrict__ Vt) {
  __shared__ u16 tile[64][65];
  int bh = blockIdx.x >> 5;
  int st = blockIdx.x & 31;
  int b = bh >> 4, h = bh & 15;
  int s0 = st << 6;
  int tid = threadIdx.x;
#pragma unroll
  for (int rr = 0; rr < 16; rr++) {
    int idx = rr * 256 + tid;
    int sl = idx >> 6, d = idx & 63;
    tile[d][sl] = Vb[(size_t)(b * S_ + s0 + sl) * 1024 + h * 64 + d];
  }
  __syncthreads();
#pragma unroll
  for (int rr = 0; rr < 16; rr++) {
    int idx = rr * 256 + tid;
    int d = idx >> 6, sl = idx & 63;
    Vt[(size_t)(bh * 64 + d) * 2048 + s0 + sl] = tile[d][sl];
  }
}

// ---------------- Flash attention v4 ----------------------------------------
// 2048 blocks: one 64-row q-tile each, heavy-first dispatch order (qtile=31
// first), XCD bits keep 8 bh per XCD. 4 waves x 16 q-rows. Swapped QK^T
// (lane owns q-row = lane&15). Softmax in log2 domain (log2e folded into Q
// scale, exp2f) + defer-rescale (THR=8). KVBLK=64 in swizzled LDS.
__global__ __launch_bounds__(256) void k_attn4(const u16* __restrict__ Q,
                                               const u16* __restrict__ Kb,
                                               const u16* __restrict__ Vt,
                                               u16* __restrict__ O) {
  __shared__ u16 Ks[64 * 64];       // [k(64)][d(64)] swizzled
  __shared__ u16 Vs[64 * 64];       // [d(64)][kv(64)] swizzled
  __shared__ u16 Ps[4 * 16 * 64];   // per-wave [q(16)][k(64)] swizzled

  // bits 0-2: xcd, bits 3-5: bh-within-xcd, bits 6-10: tier (heavy first)
  const int bh = (blockIdx.x & 7) * 8 + ((blockIdx.x >> 3) & 7);
  const int qtile = 31 - (blockIdx.x >> 6);
  const int b = bh >> 4, h = bh & 15;
  const int tid = threadIdx.x;
  const int lane = tid & 63, w = tid >> 6;
  const int g = lane >> 4, r = lane & 15;

  const u16* Kbase = Kb + (size_t)(b * S_) * 1024 + h * 64;
  const u16* Vbase = Vt + (size_t)bh * 64 * 2048;

  const int srow = tid >> 3;
  const int ssw = (srow & 7) * 8;
  const int scol = ((tid & 7) * 8) ^ ssw;         // pre-swizzled source col (u16)
  const int rsw = (r & 7) * 8;                    // read/P-write swizzle (u16)

  u16* pbase = Ps + (w << 10) + (r << 6);         // this lane's P row (q = r)

  const int qbase = qtile << 6;
  const int qrow0 = qbase + (w << 4);             // wave's first q-row

  const u16* qrow = Q + (size_t)(b * S_ + qrow0 + r) * 1024 + h * 64;
  bf16x8 qf0 = *reinterpret_cast<const bf16x8*>(qrow + g * 8);
  bf16x8 qf1 = *reinterpret_cast<const bf16x8*>(qrow + 32 + g * 8);

  f32x4 o_acc[4] = {};
  float m_run = -1e30f, l_run = 0.f;

  for (int k0 = 0; k0 <= qbase; k0 += 64) {
    gload_lds16(Kbase + (size_t)(k0 + srow) * 1024 + scol, Ks + tid * 8);
    gload_lds16(Kbase + (size_t)(k0 + srow + 32) * 1024 + scol, Ks + tid * 8 + 2048);
    gload_lds16(Vbase + (size_t)srow * 2048 + k0 + scol, Vs + tid * 8);
    gload_lds16(Vbase + (size_t)(srow + 32) * 2048 + k0 + scol, Vs + tid * 8 + 2048);
    __syncthreads();

    // ---- swapped QK^T: lane (r,g) gets S[k=k0+kt*16+g*4+j][q=qrow0+r] ----
    float sv[4][4];
#pragma unroll
    for (int kt = 0; kt < 4; kt++)
#pragma unroll
      for (int j = 0; j < 4; j++) sv[kt][j] = -1e30f;

    const int rem = (qrow0 + 15 - k0) >> 4;       // wave-uniform
    const int ktlim = rem >= 3 ? 4 : rem + 1;
    const bool needmask = (k0 == qbase);          // only diagonal tile

#pragma unroll
    for (int kt = 0; kt < 4; kt++) {
      if (kt < ktlim) {
        const int krow = kt * 16 + r;
        bf16x8 kf0 = *reinterpret_cast<const bf16x8*>(&Ks[krow * 64 + ((g * 8) ^ rsw)]);
        bf16x8 kf1 = *reinterpret_cast<const bf16x8*>(&Ks[krow * 64 + ((32 + g * 8) ^ rsw)]);
        f32x4 sa = {};
        sa = __builtin_amdgcn_mfma_f32_16x16x32_bf16(kf0, qf0, sa, 0, 0, 0);
        sa = __builtin_amdgcn_mfma_f32_16x16x32_bf16(kf1, qf1, sa, 0, 0, 0);
#pragma unroll
        for (int j = 0; j < 4; j++) sv[kt][j] = sa[j];
      }
    }

    if (needmask) {
      const int qg = qrow0 + r;
#pragma unroll
      for (int kt = 0; kt < 4; kt++)
#pragma unroll
        for (int j = 0; j < 4; j++)
          if (k0 + kt * 16 + g * 4 + j > qg) sv[kt][j] = -1e30f;
    }

    // ---- tile max: in-lane tree + 2 shuffles (lane owns q = r) ----
    float mx = -1e30f;
#pragma unroll
    for (int kt = 0; kt < 4; kt++) {
      float a = fmaxf(sv[kt][0], sv[kt][1]);
      float c = fmaxf(sv[kt][2], sv[kt][3]);
      mx = fmaxf(mx, fmaxf(a, c));
    }
    mx = fmaxf(mx, __shfl_xor(mx, 16));
    mx = fmaxf(mx, __shfl_xor(mx, 32));

    // ---- defer-rescale (T13): skip when max didn't grow by > 8 (log2) ----
    if (!__all(mx - m_run <= 8.f)) {
      const float mnew = fmaxf(m_run, mx);
      const float sc = exp2f(m_run - mnew);
      m_run = mnew;
      l_run *= sc;
#pragma unroll
      for (int j = 0; j < 4; j++) {
        const float scq = __shfl(sc, 4 * g + j);
#pragma unroll
        for (int dt = 0; dt < 4; dt++) o_acc[dt][j] *= scq;
      }
    }

    float pp[4][4], psum = 0.f;
#pragma unroll
    for (int kt = 0; kt < 4; kt++)
#pragma unroll
      for (int j = 0; j < 4; j++) {
        pp[kt][j] = exp2f(sv[kt][j] - m_run);
        psum += pp[kt][j];
      }
    psum += __shfl_xor(psum, 16);
    psum += __shfl_xor(psum, 32);
    l_run += psum;

    // P pack + swizzled b64 writes: row q = r, cols kt*16+g*4..+3
#pragma unroll
    for (int kt = 0; kt < 4; kt++) {
      ushort4 pw;
      pw.x = f2bf_hw(pp[kt][0]); pw.y = f2bf_hw(pp[kt][1]);
      pw.z = f2bf_hw(pp[kt][2]); pw.w = f2bf_hw(pp[kt][3]);
      *reinterpret_cast<ushort4*>(pbase + ((kt * 16 + g * 4) ^ rsw)) = pw;
    }
    asm volatile("s_waitcnt lgkmcnt(0)" ::: "memory");

    // ---- PV: A = P (q rows = lane&15), B = V^T ----
#pragma unroll
    for (int kc = 0; kc < 2; kc++) {
      const int cb = (kc * 32 + g * 8);
      bf16x8 pf = *reinterpret_cast<const bf16x8*>(pbase + (cb ^ rsw));
#pragma unroll
      for (int dt = 0; dt < 4; dt++) {
        bf16x8 vf = *reinterpret_cast<const bf16x8*>(&Vs[(dt * 16 + r) * 64 + (cb ^ rsw)]);
        o_acc[dt] = __builtin_amdgcn_mfma_f32_16x16x32_bf16(pf, vf, o_acc[dt], 0, 0, 0);
      }
    }
    __syncthreads();
  }

  // epilogue: o_acc[dt][j] = O[q = qrow0+g*4+j][d = dt*16+r]
  u16* orow = O + (size_t)(b * S_ + qrow0) * 1024 + h * 64;
#pragma unroll
  for (int j = 0; j < 4; j++) {
    const float ln = __shfl(l_run, 4 * g + j);
#pragma unroll
    for (int dt = 0; dt < 4; dt++)
      orow[(size_t)(g * 4 + j) * 1024 + dt * 16 + r] = f2bf(o_acc[dt][j] / ln);
  }
}

// ---------------- host side ----------------
extern "C" void kernel_launch(void* const* d_in, const int* in_sizes, int n_in,
                              void* d_out, int out_size, void* d_ws, size_t ws_size,
                              hipStream_t stream) {
  const float* x  = (const float*)d_in[0];
  const int*   pos = (const int*)d_in[1];
  const float* Wq = (const float*)d_in[2];
  const float* Wk = (const float*)d_in[3];
  const float* Wv = (const float*)d_in[4];
  const float* Wo = (const float*)d_in[5];
  float* out = (float*)d_out;

  char* ws = (char*)d_ws;
  size_t off = 0;
  auto alloc = [&](size_t bytes) {
    void* p = ws + off;
    off += (bytes + 255) & ~(size_t)255;
    return p;
  };
  const size_t XB = (size_t)8192 * 1024 * 2;  // bf16 [B*S][D]
  u16* xb  = (u16*)alloc(XB);
  u16* wqb = (u16*)alloc((size_t)1024 * 1024 * 2);   // contiguous ->
  u16* wkb = (u16*)alloc((size_t)1024 * 1024 * 2);   //   Wcat[3072][1024]
  u16* wvb = (u16*)alloc((size_t)1024 * 1024 * 2);
  u16* wob = (u16*)alloc((size_t)1024 * 1024 * 2);
  u16* qb  = (u16*)alloc(XB);                        // contiguous ->
  u16* kb  = (u16*)alloc(XB);                        //   Ccat: q|k|v
  u16* vb  = (u16*)alloc(XB);
  u16* vt  = (u16*)alloc(XB);
  float2* tab = (float2*)alloc((size_t)2048 * 32 * sizeof(float2));
  u16* ob = vb;  // alias: vb dead after transpose

  // converts
  k_f32_to_bf16<<<8192, 256, 0, stream>>>(x, xb, 2097152);
  k_f32_to_bf16<<<1024, 256, 0, stream>>>(Wq, wqb, 262144);
  k_f32_to_bf16<<<1024, 256, 0, stream>>>(Wk, wkb, 262144);
  k_f32_to_bf16<<<1024, 256, 0, stream>>>(Wv, wvb, 262144);
  k_f32_to_bf16<<<1024, 256, 0, stream>>>(Wo, wob, 262144);
  k_rope_table<<<256, 256, 0, stream>>>(pos, tab);

  // fused QKV projection (M=8192, Ncat=3072, K=1024)
  k_gemm_qkv<<<1536, 256, 0, stream>>>(xb, wqb, qb);

  // RoPE; Q gets 1/sqrt(dk) * log2(e) folded in (softmax in log2 domain)
  k_rope_apply<<<16384, 256, 0, stream>>>(qb, tab, 0.125f * LOG2E);
  k_rope_apply<<<16384, 256, 0, stream>>>(kb, tab, 1.0f);

  // V transpose for PV fragment loads
  k_transpose_v<<<2048, 256, 0, stream>>>(vb, vt);

  // flash attention v4: 64 bh x 32 q-tiles, heavy-first
  k_attn4<<<2048, 256, 0, stream>>>(qb, kb, vt, ob);

  // output projection -> f32 out
  k_gemm_bt<<<512, 256, 0, stream>>>(ob, wob, out, 8192, 1024, 1024);
}